// Round 1
// baseline (74.713 us; speedup 1.0000x reference)
//
#include <hip/hip_runtime.h>

// Problem constants (match reference setup_inputs)
#define BB 4
#define HH 1024
#define WW 1024
#define NC 12
#define GD 16
#define GH 16
#define GW 8
#define GRID_ELEMS (BB*NC*GD*GH*GW)   // 98304

// ---------------------------------------------------------------------------
// Transpose grid (b, c, z, y, x) -> (b, y, x, z, c) so the 12 channels of a
// corner are contiguous (3x float4) and z-neighbors are 48B apart.
// ---------------------------------------------------------------------------
__global__ __launch_bounds__(256) void tr_grid(const float* __restrict__ g,
                                               float* __restrict__ t) {
    int idx = blockIdx.x * 256 + threadIdx.x;
    if (idx >= GRID_ELEMS) return;
    int x = idx & 7;            // Wg = 8
    int y = (idx >> 3) & 15;    // Hg = 16
    int z = (idx >> 7) & 15;    // D  = 16
    int c = (idx >> 11) % NC;   // C  = 12
    int b = idx / (NC << 11);
    t[(((b*GH + y)*GW + x)*GD + z)*NC + c] = g[idx];
}

__device__ __forceinline__ void pixel_setup(int x, int y, float lum,
    int& x0, int& x1, int& y0, int& y1, int& z0, int& z1,
    float& wx, float& wy, float& wz)
{
    float ux = fminf(fmaxf(x * (7.0f  / 1023.0f), 0.0f), 7.0f);
    float uy = fminf(fmaxf(y * (15.0f / 1023.0f), 0.0f), 15.0f);
    float uz = fminf(fmaxf(lum * 15.0f,           0.0f), 15.0f);
    x0 = (int)ux; y0 = (int)uy; z0 = (int)uz;    // non-negative -> trunc == floor
    x1 = min(x0 + 1, GW - 1);
    y1 = min(y0 + 1, GH - 1);
    z1 = min(z0 + 1, GD - 1);
    wx = ux - (float)x0; wy = uy - (float)y0; wz = uz - (float)z0;
}

// ---------------------------------------------------------------------------
// Main kernel: one thread per pixel. Grid gather via transposed layout.
// ---------------------------------------------------------------------------
__global__ __launch_bounds__(256) void bgrid_apply(const float* __restrict__ img,
                                                   const float* __restrict__ tg,
                                                   float* __restrict__ out)
{
    const int x = blockIdx.x * 256 + threadIdx.x;
    const int y = blockIdx.y;
    const int b = blockIdx.z;
    const size_t plane = (size_t)HH * WW;
    const size_t pix = (size_t)b * 3 * plane + (size_t)y * WW + x;

    const float r  = img[pix];
    const float g  = img[pix + plane];
    const float bl = img[pix + 2 * plane];
    const float lum = 0.299f * r + 0.587f * g + 0.114f * bl;

    int x0, x1, y0, y1, z0, z1; float wx, wy, wz;
    pixel_setup(x, y, lum, x0, x1, y0, y1, z0, z1, wx, wy, wz);

    const float* gb = tg + (size_t)b * (GH * GW * GD * NC);

    float acc[12];
#pragma unroll
    for (int i = 0; i < 12; i++) acc[i] = 0.0f;

    const float cw[4]    = { (1.f - wx) * (1.f - wy), wx * (1.f - wy),
                             (1.f - wx) * wy,         wx * wy };
    const int   cy[4]    = { y0, y0, y1, y1 };
    const int   cx[4]    = { x0, x1, x0, x1 };

#pragma unroll
    for (int k = 0; k < 4; k++) {
        const float* col = gb + (size_t)((cy[k] * GW + cx[k]) * GD) * NC;
        const float w0 = cw[k] * (1.f - wz);
        const float w1 = cw[k] * wz;
        const float4* p0 = (const float4*)(col + z0 * NC);  // 48B-aligned
        const float4* p1 = (const float4*)(col + z1 * NC);
#pragma unroll
        for (int q = 0; q < 3; q++) {
            const float4 a = p0[q];
            const float4 c = p1[q];
            acc[4*q + 0] += w0 * a.x + w1 * c.x;
            acc[4*q + 1] += w0 * a.y + w1 * c.y;
            acc[4*q + 2] += w0 * a.z + w1 * c.z;
            acc[4*q + 3] += w0 * a.w + w1 * c.w;
        }
    }

    float o0 = acc[0] * r + acc[1] * g + acc[2] * bl + acc[9];
    float o1 = acc[3] * r + acc[4] * g + acc[5] * bl + acc[10];
    float o2 = acc[6] * r + acc[7] * g + acc[8] * bl + acc[11];
    o0 = fminf(fmaxf(o0, 0.0f), 1.0f);
    o1 = fminf(fmaxf(o1, 0.0f), 1.0f);
    o2 = fminf(fmaxf(o2, 0.0f), 1.0f);

    out[pix]             = o0;
    out[pix + plane]     = o1;
    out[pix + 2 * plane] = o2;
}

// ---------------------------------------------------------------------------
// Fallback (no workspace): gather from the original (b,c,z,y,x) layout.
// Correct but slow; only used if ws_size is too small for the transpose.
// ---------------------------------------------------------------------------
__global__ __launch_bounds__(256) void bgrid_apply_direct(const float* __restrict__ img,
                                                          const float* __restrict__ gr,
                                                          float* __restrict__ out)
{
    const int x = blockIdx.x * 256 + threadIdx.x;
    const int y = blockIdx.y;
    const int b = blockIdx.z;
    const size_t plane = (size_t)HH * WW;
    const size_t pix = (size_t)b * 3 * plane + (size_t)y * WW + x;

    const float r  = img[pix];
    const float g  = img[pix + plane];
    const float bl = img[pix + 2 * plane];
    const float lum = 0.299f * r + 0.587f * g + 0.114f * bl;

    int x0, x1, y0, y1, z0, z1; float wx, wy, wz;
    pixel_setup(x, y, lum, x0, x1, y0, y1, z0, z1, wx, wy, wz);

    const float cw[4] = { (1.f - wx) * (1.f - wy), wx * (1.f - wy),
                          (1.f - wx) * wy,         wx * wy };
    const int cy[4] = { y0, y0, y1, y1 };
    const int cx[4] = { x0, x1, x0, x1 };

    const float* gb = gr + (size_t)b * NC * GD * GH * GW;
    float acc[12];
#pragma unroll
    for (int c = 0; c < 12; c++) {
        const float* bc = gb + (size_t)c * GD * GH * GW;
        float s = 0.0f;
#pragma unroll
        for (int k = 0; k < 4; k++) {
            const float v0 = bc[(z0 * GH + cy[k]) * GW + cx[k]];
            const float v1 = bc[(z1 * GH + cy[k]) * GW + cx[k]];
            s += cw[k] * ((1.f - wz) * v0 + wz * v1);
        }
        acc[c] = s;
    }

    float o0 = acc[0] * r + acc[1] * g + acc[2] * bl + acc[9];
    float o1 = acc[3] * r + acc[4] * g + acc[5] * bl + acc[10];
    float o2 = acc[6] * r + acc[7] * g + acc[8] * bl + acc[11];
    out[pix]             = fminf(fmaxf(o0, 0.0f), 1.0f);
    out[pix + plane]     = fminf(fmaxf(o1, 0.0f), 1.0f);
    out[pix + 2 * plane] = fminf(fmaxf(o2, 0.0f), 1.0f);
}

extern "C" void kernel_launch(void* const* d_in, const int* in_sizes, int n_in,
                              void* d_out, int out_size, void* d_ws, size_t ws_size,
                              hipStream_t stream) {
    const float* grid  = (const float*)d_in[0];
    const float* image = (const float*)d_in[1];
    float* out = (float*)d_out;

    const size_t need = (size_t)GRID_ELEMS * sizeof(float);  // 384 KiB
    dim3 blk(256);
    dim3 gmain(WW / 256, HH, BB);

    if (ws_size >= need) {
        float* tg = (float*)d_ws;
        tr_grid<<<dim3((GRID_ELEMS + 255) / 256), blk, 0, stream>>>(grid, tg);
        bgrid_apply<<<gmain, blk, 0, stream>>>(image, tg, out);
    } else {
        bgrid_apply_direct<<<gmain, blk, 0, stream>>>(image, grid, out);
    }
}

// Round 2
// 24.228 us; speedup vs baseline: 3.0838x; 3.0838x over previous
//
#include <hip/hip_runtime.h>

// Problem constants (match reference setup_inputs)
#define BB 4
#define HH 1024
#define WW 1024
#define NC 12
#define GD 16
#define GH 16
#define GW 8

// LDS slab F[x][z][c]: z-stride padded to 52 floats (208 B) so that the
// quad-bank group (addr/16 mod 8) = (5*z + q) mod 8 -> 16 random z values
// spread over 8 groups (<=2-way conflict, ~free). x-stride 832 floats.
#define ZS 52
#define XS (GD * ZS)          // 832
#define FSZ (GW * XS)         // 6656 floats = 26624 B

__global__ __launch_bounds__(256) void bgrid_row(const float* __restrict__ img,
                                                 const float* __restrict__ grid,
                                                 float* __restrict__ out)
{
    const int y = blockIdx.x;
    const int b = blockIdx.y;
    const int tid = threadIdx.x;

    __shared__ __align__(16) float F[FSZ];

    // ---- per-row y interpolation constants (block-uniform) ----
    float uy = fminf(fmaxf(y * (15.0f / 1023.0f), 0.0f), 15.0f);
    int y0 = (int)uy;
    int y1 = min(y0 + 1, GH - 1);
    float wy = uy - (float)y0;

    // ---- stage y-lerped grid slab into LDS: F[x][z][c] ----
    const float* gb = grid + (size_t)b * (NC * GD * GH * GW); // [c][z][y][x]
#pragma unroll
    for (int j = 0; j < 6; j++) {
        int t = tid + 256 * j;          // t in [0, 1536)
        int x = t & 7;
        int z = (t >> 3) & 15;
        int c = t >> 7;                 // 0..11
        int gi = (c * GD + z) * (GH * GW) + x;
        float g0 = gb[gi + y0 * GW];
        float g1 = gb[gi + y1 * GW];
        F[x * XS + z * ZS + c] = g0 + wy * (g1 - g0);
    }
    __syncthreads();

    // ---- process 4 pixels per thread with float4 I/O ----
    const size_t plane = (size_t)HH * WW;
    const size_t rowoff = (size_t)b * 3 * plane + (size_t)y * WW;
    const float4 r4 = *(const float4*)(img + rowoff + 4 * tid);
    const float4 g4 = *(const float4*)(img + rowoff + plane + 4 * tid);
    const float4 b4 = *(const float4*)(img + rowoff + 2 * plane + 4 * tid);

    float4 o0, o1, o2;
    float* o0p = (float*)&o0; float* o1p = (float*)&o1; float* o2p = (float*)&o2;
    const float* rp = (const float*)&r4;
    const float* gp = (const float*)&g4;
    const float* bp = (const float*)&b4;

#pragma unroll
    for (int p = 0; p < 4; p++) {
        const int px = 4 * tid + p;
        const float r = rp[p], g = gp[p], bl = bp[p];

        float ux = fminf(fmaxf(px * (7.0f / 1023.0f), 0.0f), 7.0f);
        int x0 = (int)ux;
        int x1 = min(x0 + 1, GW - 1);
        float wx = ux - (float)x0;

        float lum = 0.299f * r + 0.587f * g + 0.114f * bl;
        float uz = fminf(fmaxf(lum * 15.0f, 0.0f), 15.0f);
        int z0 = (int)uz;
        int z1 = min(z0 + 1, GD - 1);
        float wz = uz - (float)z0;

        const float* f00 = &F[x0 * XS + z0 * ZS];  // (x0,z0)
        const float* f10 = &F[x1 * XS + z0 * ZS];  // (x1,z0)
        const float* f01 = &F[x0 * XS + z1 * ZS];  // (x0,z1)
        const float* f11 = &F[x1 * XS + z1 * ZS];  // (x1,z1)

        float cf[12];
#pragma unroll
        for (int q = 0; q < 3; q++) {
            const float4 a = *(const float4*)(f00 + 4 * q);
            const float4 bq = *(const float4*)(f10 + 4 * q);
            const float4 c = *(const float4*)(f01 + 4 * q);
            const float4 d = *(const float4*)(f11 + 4 * q);
            // lerp in x, then z
            float m0x = a.x + wx * (bq.x - a.x), m1x = c.x + wx * (d.x - c.x);
            float m0y = a.y + wx * (bq.y - a.y), m1y = c.y + wx * (d.y - c.y);
            float m0z = a.z + wx * (bq.z - a.z), m1z = c.z + wx * (d.z - c.z);
            float m0w = a.w + wx * (bq.w - a.w), m1w = c.w + wx * (d.w - c.w);
            cf[4 * q + 0] = m0x + wz * (m1x - m0x);
            cf[4 * q + 1] = m0y + wz * (m1y - m0y);
            cf[4 * q + 2] = m0z + wz * (m1z - m0z);
            cf[4 * q + 3] = m0w + wz * (m1w - m0w);
        }

        float v0 = cf[0] * r + cf[1] * g + cf[2] * bl + cf[9];
        float v1 = cf[3] * r + cf[4] * g + cf[5] * bl + cf[10];
        float v2 = cf[6] * r + cf[7] * g + cf[8] * bl + cf[11];
        o0p[p] = fminf(fmaxf(v0, 0.0f), 1.0f);
        o1p[p] = fminf(fmaxf(v1, 0.0f), 1.0f);
        o2p[p] = fminf(fmaxf(v2, 0.0f), 1.0f);
    }

    *(float4*)(out + rowoff + 4 * tid) = o0;
    *(float4*)(out + rowoff + plane + 4 * tid) = o1;
    *(float4*)(out + rowoff + 2 * plane + 4 * tid) = o2;
}

extern "C" void kernel_launch(void* const* d_in, const int* in_sizes, int n_in,
                              void* d_out, int out_size, void* d_ws, size_t ws_size,
                              hipStream_t stream) {
    const float* grid  = (const float*)d_in[0];
    const float* image = (const float*)d_in[1];
    float* out = (float*)d_out;

    dim3 blk(256);
    dim3 grd(HH, BB);   // one block per (row, batch)
    bgrid_row<<<grd, blk, 0, stream>>>(image, grid, out);
}